// Round 12
// baseline (142.869 us; speedup 1.0000x reference)
//
#include <hip/hip_runtime.h>

#define NROWS 262144
#define KK 10
#define BB 3.0f
#define SROW 132                   // phase-3 row stride in f16: 264 B = 66 dw == 2 mod 4 -> conflict-free (r7: 0)
#define HS 84                      // phase-1/2 h row stride in f16: 168 B -> conflict-free (r7: 0)
#define SEGF16 (16 * SROW)         // 2112 f16 = 4224 B per tile segment
#define SENT 0.54132485f           // ln(e-1): softplus(SENT) == 1.0 (boundary derivative)
#define NBLK 4096                  // persistent blocks (16/CU); each wave does 2 tile-pairs
#define ITERS (NROWS / 32 / NBLK)  // = 2

typedef _Float16 v8h __attribute__((ext_vector_type(8)));
typedef _Float16 v4h __attribute__((ext_vector_type(4)));
typedef float v4f __attribute__((ext_vector_type(4)));

// d_ws layout: v8h frags: W0[4*64] | W1[2*4*64] | WC[2*16*64] ; then f32 slots[64]
#define W0_OFF 0
#define W1_OFF 256
#define WC_OFF 768
#define FRAG_TOTAL 2816
#define SLOTS_OFF (FRAG_TOTAL * 4)   // f32 units from ws base (FRAG_TOTAL*16 bytes)

#if __has_builtin(__builtin_amdgcn_exp2f)
__device__ __forceinline__ float ex2(float x) { return __builtin_amdgcn_exp2f(x); }
#else
__device__ __forceinline__ float ex2(float x) { return __expf(0.6931471805599453f * x); }
#endif
#if __has_builtin(__builtin_amdgcn_rcpf)
__device__ __forceinline__ float frcp(float x) { return __builtin_amdgcn_rcpf(x); }
#else
__device__ __forceinline__ float frcp(float x) { return __fdividef(1.0f, x); }
#endif

#define LOG2E 1.4426950408889634f
#define C6 (6.0f * LOG2E)          // softmax temperature 2*B = 6, folded into exp2
#define CT (2.0f * LOG2E)          // tanh: e^{2a} = 2^{CT*a}

__device__ __forceinline__ float fast_tanh(float a) {
    const float e = ex2(CT * a);
    return fmaf(-2.0f, frcp(e + 1.0f), 1.0f);
}

__device__ __forceinline__ float softplus1(float v) {
    return fmaxf(v, 0.0f) + __logf(1.0f + ex2(-LOG2E * fabsf(v)));
}

// one (row, dim) rational-quadratic spline task; reads 32 f16 via 8 conflict-free b64 loads,
// writes z, adds logdet
__device__ __forceinline__ void spline_task(
    const _Float16* __restrict__ sg, int base, float ud, int g, int d,
    float* __restrict__ out, float& ldacc)
{
    float vals[32];
    #pragma unroll
    for (int blk = 0; blk < 8; ++blk) {
        const v4h p = *(const v4h*)&sg[base + blk * 4];   // 8-B aligned ds_read_b64
        vals[4 * blk + 0] = (float)p[0];
        vals[4 * blk + 1] = (float)p[1];
        vals[4 * blk + 2] = (float)p[2];
        vals[4 * blk + 3] = (float)p[3];
    }
    // vals[0..9]=aw logits, [10..19]=ah logits, [20..28]=ad raw

    float mw = vals[0];
    #pragma unroll
    for (int i = 1; i < KK; ++i) mw = fmaxf(mw, vals[i]);
    const float mw8 = mw * C6;
    float sw = 0.0f;
    #pragma unroll
    for (int i = 0; i < KK; ++i) { vals[i] = ex2(fmaf(vals[i], C6, -mw8)); sw += vals[i]; }
    const float invw = frcp(sw);

    float mh = vals[10];
    #pragma unroll
    for (int i = 1; i < KK; ++i) mh = fmaxf(mh, vals[10 + i]);
    const float mh8 = mh * C6;
    float sh = 0.0f;
    #pragma unroll
    for (int i = 0; i < KK; ++i) { vals[10 + i] = ex2(fmaf(vals[10 + i], C6, -mh8)); sh += vals[10 + i]; }
    const float invh = frcp(sh);

    const float uc = fminf(fmaxf(ud, -BB), BB);
    const bool inside = (ud > -BB) && (ud < BB);

    // streaming bin search over RAW derivative values (sentinel: softplus(SENT)==1)
    float cw = 0.0f, ch = 0.0f;
    float xprev = -BB, yprev = -BB, rprev = SENT;
    float xk = -BB, yk = -BB, wk = 1.0f, hk2 = 1.0f, rdk = SENT, rdk1 = SENT;
    #pragma unroll
    for (int i = 0; i < KK; ++i) {
        cw += vals[i] * invw;
        ch += vals[10 + i] * invh;
        const float xnext = fmaf(6.0f, cw, -BB);
        const float ynext = fmaf(6.0f, ch, -BB);
        const float rnext = (i == KK - 1) ? SENT : vals[20 + i];
        const bool c = (i == 0) || (uc >= xprev);
        if (c) { xk = xprev; yk = yprev; wk = xnext - xprev; hk2 = ynext - yprev; rdk = rprev; rdk1 = rnext; }
        xprev = xnext; yprev = ynext; rprev = rnext;
    }
    const float dk = softplus1(rdk);
    const float dk1 = softplus1(rdk1);

    const float rwk = frcp(wk);
    const float sk = hk2 * rwk;
    const float xi = (uc - xk) * rwk;
    const float om = 1.0f - xi;
    const float denom = sk + (dk1 + dk - 2.0f * sk) * xi * om;
    const float rden = frcp(denom);
    const float ynum = sk * xi * xi + dk * xi * om;
    const float yv = yk + hk2 * ynum * rden;
    const float larg = dk1 * xi * xi + 2.0f * sk * xi * om + dk * om * om;
    const float ldet = __logf(sk * sk * larg * rden * rden);

    out[g * 16 + 8 + d] = inside ? yv : ud;
    ldacc += inside ? ldet : 0.0f;
}

// ---- prep: pack B-fragments with bias folded into k=8/k=50 row; zero logdet slots ----
__global__ __launch_bounds__(256) void nsf_prep(
    const float* __restrict__ w0, const float* __restrict__ b0,
    const float* __restrict__ w1, const float* __restrict__ b1,
    const float* __restrict__ ww, const float* __restrict__ bw,
    const float* __restrict__ wh, const float* __restrict__ bh,
    const float* __restrict__ wd, const float* __restrict__ bd,
    v8h* __restrict__ wsv, float* __restrict__ wsf)
{
    const int t = blockIdx.x * 256 + threadIdx.x;
    if (t < 64) wsf[SLOTS_OFF + t] = 0.0f;
    if (t >= FRAG_TOTAL) return;

    v8h v;
    #pragma unroll
    for (int j = 0; j < 8; ++j) v[j] = (_Float16)0.0f;

    if (t < W1_OFF) {                       // W0: 9x50 (row 8 = b0) padded to K=32, 4 col tiles
        const int tile = t >> 6, lane = t & 63, q = lane >> 4, n = tile * 16 + (lane & 15);
        if (n < 50) {
            #pragma unroll
            for (int j = 0; j < 8; ++j) {
                const int k = q * 8 + j;
                if (k < 8)       v[j] = (_Float16)w0[k * 50 + n];
                else if (k == 8) v[j] = (_Float16)b0[n];
            }
        }
    } else if (t < WC_OFF) {                // W1: 51x50 (row 50 = b1), 2 k-steps, 4 col tiles
        int p = t - W1_OFF;
        const int step = p >> 8; p &= 255;
        const int tile = p >> 6, lane = p & 63, q = lane >> 4, n = tile * 16 + (lane & 15);
        if (n < 50) {
            #pragma unroll
            for (int j = 0; j < 8; ++j) {
                const int k = step * 32 + q * 8 + j;
                if (k < 50)       v[j] = (_Float16)w1[k * 50 + n];
                else if (k == 50) v[j] = (_Float16)b1[n];
            }
        }
    } else {                                // WC: 51x256 (row 50 = bias), cols c' = d*32 + jj
        int p = t - WC_OFF;
        const int step = p >> 10; p &= 1023;
        const int tile = p >> 6, lane = p & 63, q = lane >> 4;
        const int cp = tile * 16 + (lane & 15);
        const int d = cp >> 5, jj = cp & 31;
        #pragma unroll
        for (int j = 0; j < 8; ++j) {
            const int k = step * 32 + q * 8 + j;
            float val = 0.0f;
            if (k < 50) {
                if (jj < 10)      val = ww[k * 80 + d * 10 + jj];
                else if (jj < 20) val = wh[k * 80 + d * 10 + (jj - 10)];
                else if (jj < 29) val = wd[k * 72 + d * 9 + (jj - 20)];
            } else if (k == 50) {
                if (jj < 10)      val = bw[d * 10 + jj];
                else if (jj < 20) val = bh[d * 10 + (jj - 10)];
                else if (jj < 29) val = bd[d * 9 + (jj - 20)];
            }
            v[j] = (_Float16)val;
        }
    }
    wsv[t] = v;
}

// ---- main v12: v11's persistent+prefetch structure with NBLK 2048->4096, pairs 4->2.
//      r11 confirmed cross-pair prefetch (main 70->56 us); residual ~50% stall at only
//      ~5.3 resident waves/CU, and the binding limit is now GRID SIZE (VGPR 96 allows
//      20 waves/CU, LDS allows 18 blocks/CU, launched: 8/CU). Double blocks/CU to 16:
//      ~2x resident waves converts remaining latency stalls to VALU throughput; 2
//      pairs/wave keeps the 1-deep prefetch (pair 2's loads still hidden).
__global__ __launch_bounds__(64) void nsf_main_v12(
    const float* __restrict__ x,
    const v8h* __restrict__ wsv,
    float* __restrict__ out, float* __restrict__ slots)
{
    __shared__ __align__(16) _Float16 smem[2 * SEGF16];   // 8448 B
    const int lane = threadIdx.x & 63;
    const int q = lane >> 4, l15 = lane & 15;
    _Float16* segA = &smem[0];
    _Float16* segB = &smem[SEGF16];
    const int pr = lane >> 1, pc = lane & 1;

    const float4* xv = (const float4*)x;
    float4* ov = (float4*)out;

    // prefetch registers (next pair's inputs)
    float4 ph_n = make_float4(0.f, 0.f, 0.f, 0.f);
    float uA0_n = 0.f, uA1_n = 0.f, uB0_n = 0.f, uB1_n = 0.f;
    float4 f0_n = ph_n, f1_n = ph_n, g0_n = ph_n, g1_n = ph_n;

    auto PREF = [&](int p) {
        const int R0 = p * 32;
        ph_n  = xv[(R0 + pr) * 4 + pc];
        uA0_n = x[(R0 + l15) * 16 + 8 + q];
        uA1_n = x[(R0 + l15) * 16 + 12 + q];
        uB0_n = x[(R0 + 16 + l15) * 16 + 8 + q];
        uB1_n = x[(R0 + 16 + l15) * 16 + 12 + q];
        if (lane < 16) {
            f0_n = xv[(R0 + lane) * 4 + 0];
            f1_n = xv[(R0 + lane) * 4 + 1];
            g0_n = xv[(R0 + 16 + lane) * 4 + 0];
            g1_n = xv[(R0 + 16 + lane) * 4 + 1];
        }
    };

    PREF(blockIdx.x);
    float ldacc = 0.0f;

    #pragma unroll 1
    for (int it = 0; it < ITERS; ++it) {
        // consume prefetched set (single waitcnt here), then immediately issue next prefetch
        const int pcur = it * NBLK + blockIdx.x;
        const int R0 = pcur * 32;                         // tile A: R0.., tile B: R0+16..
        const float4 phc = ph_n;
        const float uA0 = uA0_n, uA1 = uA1_n, uB0 = uB0_n, uB1 = uB1_n;
        const float4 f0 = f0_n, f1 = f1_n, g0 = g0_n, g1 = g1_n;
        if (it < ITERS - 1) PREF((it + 1) * NBLK + blockIdx.x);

        // passthrough of the 8 scale dims (coalesced float4)
        ov[(R0 + pr) * 4 + pc] = phc;

        // ---- phase 0: zd fragments for both tiles (k<8 real, k=8 -> 1.0 bias row) ----
        v8h aA, aB;
        #pragma unroll
        for (int j = 0; j < 8; ++j) { aA[j] = (_Float16)0.0f; aB[j] = (_Float16)0.0f; }
        if (lane < 16) {
            aA[0] = (_Float16)f0.x; aA[1] = (_Float16)f0.y; aA[2] = (_Float16)f0.z; aA[3] = (_Float16)f0.w;
            aA[4] = (_Float16)f1.x; aA[5] = (_Float16)f1.y; aA[6] = (_Float16)f1.z; aA[7] = (_Float16)f1.w;
            aB[0] = (_Float16)g0.x; aB[1] = (_Float16)g0.y; aB[2] = (_Float16)g0.z; aB[3] = (_Float16)g0.w;
            aB[4] = (_Float16)g1.x; aB[5] = (_Float16)g1.y; aB[6] = (_Float16)g1.z; aB[7] = (_Float16)g1.w;
        }
        if (q == 1) { aA[0] = (_Float16)1.0f; aB[0] = (_Float16)1.0f; }   // k=8: bias row

        // ---- phase 1: h1 = tanh(zd @ [w0;b0]) -> rows stride HS=84 ----
        #pragma unroll
        for (int t = 0; t < 4; ++t) {
            const v8h b = wsv[W0_OFF + t * 64 + lane];
            v4f cA = __builtin_amdgcn_mfma_f32_16x16x32_f16(b, aA, (v4f)(0.0f), 0, 0, 0);
            v4f cB = __builtin_amdgcn_mfma_f32_16x16x32_f16(b, aB, (v4f)(0.0f), 0, 0, 0);
            v4h pA, pB;
            #pragma unroll
            for (int rg = 0; rg < 4; ++rg) {
                pA[rg] = (_Float16)fast_tanh(cA[rg]);
                pB[rg] = (_Float16)fast_tanh(cB[rg]);
            }
            const int o = l15 * HS + t * 16 + q * 4;
            *(v4h*)&segA[o] = pA;
            *(v4h*)&segB[o] = pB;
        }

        // ---- phase 2: h2 = tanh(h1 @ [w1;b1]) (in-order DS: reads precede overwrites) ----
        v8h A0A, A1A, A0B, A1B;
        {
            const int o0 = l15 * HS + q * 8;
            const int o1 = l15 * HS + 32 + q * 8;
            const v4h a0l = *(const v4h*)&segA[o0], a0h = *(const v4h*)&segA[o0 + 4];
            const v4h a1l = *(const v4h*)&segA[o1], a1h = *(const v4h*)&segA[o1 + 4];
            const v4h b0l = *(const v4h*)&segB[o0], b0h = *(const v4h*)&segB[o0 + 4];
            const v4h b1l = *(const v4h*)&segB[o1], b1h = *(const v4h*)&segB[o1 + 4];
            #pragma unroll
            for (int j = 0; j < 4; ++j) {
                A0A[j] = a0l[j]; A0A[4 + j] = a0h[j];
                A1A[j] = a1l[j]; A1A[4 + j] = a1h[j];
                A0B[j] = b0l[j]; A0B[4 + j] = b0h[j];
                A1B[j] = b1l[j]; A1B[4 + j] = b1h[j];
            }
        }
        if (q == 2) { A1A[2] = (_Float16)1.0f; A1B[2] = (_Float16)1.0f; }   // k=50: bias row
        #pragma unroll
        for (int t = 0; t < 4; ++t) {
            const v8h bf0 = wsv[W1_OFF + t * 64 + lane];
            const v8h bf1 = wsv[W1_OFF + 256 + t * 64 + lane];
            v4f cA = __builtin_amdgcn_mfma_f32_16x16x32_f16(bf0, A0A, (v4f)(0.0f), 0, 0, 0);
            cA = __builtin_amdgcn_mfma_f32_16x16x32_f16(bf1, A1A, cA, 0, 0, 0);
            v4f cB = __builtin_amdgcn_mfma_f32_16x16x32_f16(bf0, A0B, (v4f)(0.0f), 0, 0, 0);
            cB = __builtin_amdgcn_mfma_f32_16x16x32_f16(bf1, A1B, cB, 0, 0, 0);
            v4h pA, pB;
            #pragma unroll
            for (int rg = 0; rg < 4; ++rg) {
                pA[rg] = (_Float16)fast_tanh(cA[rg]);
                pB[rg] = (_Float16)fast_tanh(cB[rg]);
            }
            const int o = l15 * HS + t * 16 + q * 4;
            *(v4h*)&segA[o] = pA;
            *(v4h*)&segB[o] = pB;
        }

        // ---- phase 3 h2-frags (reload, b64 pairs) ----
        {
            const int o0 = l15 * HS + q * 8;
            const int o1 = l15 * HS + 32 + q * 8;
            const v4h a0l = *(const v4h*)&segA[o0], a0h = *(const v4h*)&segA[o0 + 4];
            const v4h a1l = *(const v4h*)&segA[o1], a1h = *(const v4h*)&segA[o1 + 4];
            const v4h b0l = *(const v4h*)&segB[o0], b0h = *(const v4h*)&segB[o0 + 4];
            const v4h b1l = *(const v4h*)&segB[o1], b1h = *(const v4h*)&segB[o1 + 4];
            #pragma unroll
            for (int j = 0; j < 4; ++j) {
                A0A[j] = a0l[j]; A0A[4 + j] = a0h[j];
                A1A[j] = a1l[j]; A1A[4 + j] = a1h[j];
                A0B[j] = b0l[j]; A0B[4 + j] = b0h[j];
                A1B[j] = b1l[j]; A1B[4 + j] = b1h[j];
            }
        }
        if (q == 2) { A1A[2] = (_Float16)1.0f; A1B[2] = (_Float16)1.0f; }   // k=50: bias row

        // ---- phase 3 first half: dims 0-3 (t = 0..7) -> slots 0..3, stride SROW=132 ----
        #pragma unroll 2
        for (int t = 0; t < 8; ++t) {
            const v8h bf0 = wsv[WC_OFF + t * 64 + lane];
            const v8h bf1 = wsv[WC_OFF + 1024 + t * 64 + lane];
            v4f cA = __builtin_amdgcn_mfma_f32_16x16x32_f16(bf0, A0A, (v4f)(0.0f), 0, 0, 0);
            cA = __builtin_amdgcn_mfma_f32_16x16x32_f16(bf1, A1A, cA, 0, 0, 0);
            v4f cB = __builtin_amdgcn_mfma_f32_16x16x32_f16(bf0, A0B, (v4f)(0.0f), 0, 0, 0);
            cB = __builtin_amdgcn_mfma_f32_16x16x32_f16(bf1, A1B, cB, 0, 0, 0);
            v4h pA, pB;
            #pragma unroll
            for (int rg = 0; rg < 4; ++rg) { pA[rg] = (_Float16)cA[rg]; pB[rg] = (_Float16)cB[rg]; }
            const int o = l15 * SROW + t * 16 + q * 4;
            *(v4h*)&segA[o] = pA;
            *(v4h*)&segB[o] = pB;
        }

        // ---- epilogue tasks tt=0 (d = q): in-order DS reads precede second-half overwrites ----
        spline_task(segA, l15 * SROW + q * 32, uA0, R0 + l15, q, out, ldacc);
        spline_task(segB, l15 * SROW + q * 32, uB0, R0 + 16 + l15, q, out, ldacc);

        // ---- phase 3 second half: dims 4-7 (t = 8..15) -> SAME slots 0..3 (buffer reuse) ----
        #pragma unroll 2
        for (int t = 8; t < 16; ++t) {
            const v8h bf0 = wsv[WC_OFF + t * 64 + lane];
            const v8h bf1 = wsv[WC_OFF + 1024 + t * 64 + lane];
            v4f cA = __builtin_amdgcn_mfma_f32_16x16x32_f16(bf0, A0A, (v4f)(0.0f), 0, 0, 0);
            cA = __builtin_amdgcn_mfma_f32_16x16x32_f16(bf1, A1A, cA, 0, 0, 0);
            v4f cB = __builtin_amdgcn_mfma_f32_16x16x32_f16(bf0, A0B, (v4f)(0.0f), 0, 0, 0);
            cB = __builtin_amdgcn_mfma_f32_16x16x32_f16(bf1, A1B, cB, 0, 0, 0);
            v4h pA, pB;
            #pragma unroll
            for (int rg = 0; rg < 4; ++rg) { pA[rg] = (_Float16)cA[rg]; pB[rg] = (_Float16)cB[rg]; }
            const int o = l15 * SROW + (t - 8) * 16 + q * 4;
            *(v4h*)&segA[o] = pA;
            *(v4h*)&segB[o] = pB;
        }

        // ---- epilogue tasks tt=1 (d = q+4, same slots) ----
        spline_task(segA, l15 * SROW + q * 32, uA1, R0 + l15, q + 4, out, ldacc);
        spline_task(segB, l15 * SROW + q * 32, uB1, R0 + 16 + l15, q + 4, out, ldacc);
    }

    // ---- logdet: one wave shuffle-reduce + atomic per persistent wave ----
    #pragma unroll
    for (int off = 32; off > 0; off >>= 1) ldacc += __shfl_down(ldacc, off);
    if (lane == 0) atomicAdd(&slots[blockIdx.x & 63], ldacc);
}

// ---- finish: sum the 64 partial slots into the scalar logdet output ----
__global__ void nsf_finish(const float* __restrict__ slots, float* __restrict__ ldp) {
    float v = slots[threadIdx.x];
    #pragma unroll
    for (int off = 32; off > 0; off >>= 1) v += __shfl_down(v, off);
    if (threadIdx.x == 0) *ldp = v;
}

extern "C" void kernel_launch(void* const* d_in, const int* in_sizes, int n_in,
                              void* d_out, int out_size, void* d_ws, size_t ws_size,
                              hipStream_t stream) {
    const float* x  = (const float*)d_in[0];
    const float* w0 = (const float*)d_in[1];
    const float* b0 = (const float*)d_in[2];
    const float* w1 = (const float*)d_in[3];
    const float* b1 = (const float*)d_in[4];
    const float* ww = (const float*)d_in[5];
    const float* bw = (const float*)d_in[6];
    const float* wh = (const float*)d_in[7];
    const float* bh = (const float*)d_in[8];
    const float* wd = (const float*)d_in[9];
    const float* bd = (const float*)d_in[10];

    float* out = (float*)d_out;
    float* ldp = out + (size_t)NROWS * 16;   // scalar logdet sum slot
    v8h* wsv = (v8h*)d_ws;                   // 45 KB packed B-fragments (bias folded)
    float* wsf = (float*)d_ws;               // f32 view for slots
    float* slots = wsf + SLOTS_OFF;

    hipLaunchKernelGGL(nsf_prep, dim3((FRAG_TOTAL + 255) / 256), dim3(256), 0, stream,
                       w0, b0, w1, b1, ww, bw, wh, bh, wd, bd, wsv, wsf);
    hipLaunchKernelGGL(nsf_main_v12, dim3(NBLK), dim3(64), 0, stream,
                       x, wsv, out, slots);
    hipLaunchKernelGGL(nsf_finish, dim3(1), dim3(64), 0, stream, slots, ldp);
}

// Round 13
// 135.914 us; speedup vs baseline: 1.0512x; 1.0512x over previous
//
#include <hip/hip_runtime.h>

#define NROWS 262144
#define KK 10
#define BB 3.0f
#define SROW 132                   // phase-3 row stride in f16: 264 B = 66 dw == 2 mod 4 -> conflict-free (r7: 0)
#define HS 84                      // phase-1/2 h row stride in f16: 168 B -> conflict-free (r7: 0)
#define SEGF16 (16 * SROW)         // 2112 f16 = 4224 B per tile segment
#define SENT 0.54132485f           // ln(e-1): softplus(SENT) == 1.0 (boundary derivative)
#define NBLK 2048                  // persistent blocks (r11-proven best: 8/CU, 4 pairs/wave)
#define ITERS (NROWS / 32 / NBLK)  // = 4

typedef _Float16 v8h __attribute__((ext_vector_type(8)));
typedef _Float16 v4h __attribute__((ext_vector_type(4)));
typedef float v4f __attribute__((ext_vector_type(4)));

// d_ws layout: v8h frags: W0[4*64] | W1[2*4*64] | WC[2*16*64] ; then f32 slots[64]
#define W0_OFF 0
#define W1_OFF 256
#define WC_OFF 768
#define FRAG_TOTAL 2816
#define SLOTS_OFF (FRAG_TOTAL * 4)   // f32 units from ws base (FRAG_TOTAL*16 bytes)

#if __has_builtin(__builtin_amdgcn_exp2f)
__device__ __forceinline__ float ex2(float x) { return __builtin_amdgcn_exp2f(x); }
#else
__device__ __forceinline__ float ex2(float x) { return __expf(0.6931471805599453f * x); }
#endif
#if __has_builtin(__builtin_amdgcn_rcpf)
__device__ __forceinline__ float frcp(float x) { return __builtin_amdgcn_rcpf(x); }
#else
__device__ __forceinline__ float frcp(float x) { return __fdividef(1.0f, x); }
#endif

#define LOG2E 1.4426950408889634f
#define C6 (6.0f * LOG2E)          // softmax temperature 2*B = 6, folded into exp2
#define CT (2.0f * LOG2E)          // tanh: e^{2a} = 2^{CT*a}

__device__ __forceinline__ float fast_tanh(float a) {
    const float e = ex2(CT * a);
    return fmaf(-2.0f, frcp(e + 1.0f), 1.0f);
}

__device__ __forceinline__ float softplus1(float v) {
    return fmaxf(v, 0.0f) + __logf(1.0f + ex2(-LOG2E * fabsf(v)));
}

// one (row, dim) rational-quadratic spline task; reads 32 f16 via 8 conflict-free b64 loads,
// writes z, adds logdet. v13: bin search runs on RAW exp cumsums (normalization deferred
// out of the loop): uc >= xprev  <=>  (uc+B)*sw/6 >= cw_raw  (sw>0, monotone; boundary
// ties land in an adjacent bin where the spline is continuous). Saves ~34 VALU ops/task
// and shortens the loop-carried dependency (cw no longer waits on a multiply).
__device__ __forceinline__ void spline_task(
    const _Float16* __restrict__ sg, int base, float ud, int g, int d,
    float* __restrict__ out, float& ldacc)
{
    float vals[32];
    #pragma unroll
    for (int blk = 0; blk < 8; ++blk) {
        const v4h p = *(const v4h*)&sg[base + blk * 4];   // 8-B aligned ds_read_b64
        vals[4 * blk + 0] = (float)p[0];
        vals[4 * blk + 1] = (float)p[1];
        vals[4 * blk + 2] = (float)p[2];
        vals[4 * blk + 3] = (float)p[3];
    }
    // vals[0..9]=aw logits, [10..19]=ah logits, [20..28]=ad raw

    float mw = vals[0];
    #pragma unroll
    for (int i = 1; i < KK; ++i) mw = fmaxf(mw, vals[i]);
    const float mw8 = mw * C6;
    float sw = 0.0f;
    #pragma unroll
    for (int i = 0; i < KK; ++i) { vals[i] = ex2(fmaf(vals[i], C6, -mw8)); sw += vals[i]; }
    const float invw = frcp(sw);

    float mh = vals[10];
    #pragma unroll
    for (int i = 1; i < KK; ++i) mh = fmaxf(mh, vals[10 + i]);
    const float mh8 = mh * C6;
    float sh = 0.0f;
    #pragma unroll
    for (int i = 0; i < KK; ++i) { vals[10 + i] = ex2(fmaf(vals[10 + i], C6, -mh8)); sh += vals[10 + i]; }
    const float invh = frcp(sh);

    const float uc = fminf(fmaxf(ud, -BB), BB);
    const bool inside = (ud > -BB) && (ud < BB);
    const float T = (uc + BB) * sw * 0.16666667f;   // selection threshold in raw-cumsum domain

    // streaming bin search over RAW cumsums + RAW derivative values
    float cw = 0.0f, ch = 0.0f;
    float cwp = 0.0f, chp = 0.0f, rprev = SENT;
    float cwk0 = 0.0f, cwk1 = 0.0f, chk0 = 0.0f, chk1 = 0.0f, rdk = SENT, rdk1 = SENT;
    #pragma unroll
    for (int i = 0; i < KK; ++i) {
        cw += vals[i];
        ch += vals[10 + i];
        const float rnext = (i == KK - 1) ? SENT : vals[20 + i];
        const bool c = (i == 0) || (T >= cwp);
        if (c) { cwk0 = cwp; cwk1 = cw; chk0 = chp; chk1 = ch; rdk = rprev; rdk1 = rnext; }
        cwp = cw; chp = ch; rprev = rnext;
    }
    // deferred normalization of the selected bin only
    const float s6w = 6.0f * invw;
    const float s6h = 6.0f * invh;
    const float xk  = fmaf(s6w, cwk0, -BB);
    const float yk  = fmaf(s6h, chk0, -BB);
    const float wk  = s6w * (cwk1 - cwk0);
    const float hk2 = s6h * (chk1 - chk0);

    const float dk = softplus1(rdk);
    const float dk1 = softplus1(rdk1);

    const float rwk = frcp(wk);
    const float sk = hk2 * rwk;
    const float xi = (uc - xk) * rwk;
    const float om = 1.0f - xi;
    const float denom = sk + (dk1 + dk - 2.0f * sk) * xi * om;
    const float rden = frcp(denom);
    const float ynum = sk * xi * xi + dk * xi * om;
    const float yv = yk + hk2 * ynum * rden;
    const float larg = dk1 * xi * xi + 2.0f * sk * xi * om + dk * om * om;
    const float ldet = __logf(sk * sk * larg * rden * rden);

    out[g * 16 + 8 + d] = inside ? yv : ud;
    ldacc += inside ? ldet : 0.0f;
}

// ---- prep: pack B-fragments with bias folded into k=8/k=50 row; zero logdet slots ----
__global__ __launch_bounds__(256) void nsf_prep(
    const float* __restrict__ w0, const float* __restrict__ b0,
    const float* __restrict__ w1, const float* __restrict__ b1,
    const float* __restrict__ ww, const float* __restrict__ bw,
    const float* __restrict__ wh, const float* __restrict__ bh,
    const float* __restrict__ wd, const float* __restrict__ bd,
    v8h* __restrict__ wsv, float* __restrict__ wsf)
{
    const int t = blockIdx.x * 256 + threadIdx.x;
    if (t < 64) wsf[SLOTS_OFF + t] = 0.0f;
    if (t >= FRAG_TOTAL) return;

    v8h v;
    #pragma unroll
    for (int j = 0; j < 8; ++j) v[j] = (_Float16)0.0f;

    if (t < W1_OFF) {                       // W0: 9x50 (row 8 = b0) padded to K=32, 4 col tiles
        const int tile = t >> 6, lane = t & 63, q = lane >> 4, n = tile * 16 + (lane & 15);
        if (n < 50) {
            #pragma unroll
            for (int j = 0; j < 8; ++j) {
                const int k = q * 8 + j;
                if (k < 8)       v[j] = (_Float16)w0[k * 50 + n];
                else if (k == 8) v[j] = (_Float16)b0[n];
            }
        }
    } else if (t < WC_OFF) {                // W1: 51x50 (row 50 = b1), 2 k-steps, 4 col tiles
        int p = t - W1_OFF;
        const int step = p >> 8; p &= 255;
        const int tile = p >> 6, lane = p & 63, q = lane >> 4, n = tile * 16 + (lane & 15);
        if (n < 50) {
            #pragma unroll
            for (int j = 0; j < 8; ++j) {
                const int k = step * 32 + q * 8 + j;
                if (k < 50)       v[j] = (_Float16)w1[k * 50 + n];
                else if (k == 50) v[j] = (_Float16)b1[n];
            }
        }
    } else {                                // WC: 51x256 (row 50 = bias), cols c' = d*32 + jj
        int p = t - WC_OFF;
        const int step = p >> 10; p &= 1023;
        const int tile = p >> 6, lane = p & 63, q = lane >> 4;
        const int cp = tile * 16 + (lane & 15);
        const int d = cp >> 5, jj = cp & 31;
        #pragma unroll
        for (int j = 0; j < 8; ++j) {
            const int k = step * 32 + q * 8 + j;
            float val = 0.0f;
            if (k < 50) {
                if (jj < 10)      val = ww[k * 80 + d * 10 + jj];
                else if (jj < 20) val = wh[k * 80 + d * 10 + (jj - 10)];
                else if (jj < 29) val = wd[k * 72 + d * 9 + (jj - 20)];
            } else if (k == 50) {
                if (jj < 10)      val = bw[d * 10 + jj];
                else if (jj < 20) val = bh[d * 10 + (jj - 10)];
                else if (jj < 29) val = bd[d * 9 + (jj - 20)];
            }
            v[j] = (_Float16)val;
        }
    }
    wsv[t] = v;
}

// ---- main v13: r11's proven-best persistent structure (NBLK 2048, 4 pairs/wave,
//      1-deep cross-pair prefetch) + deferred-normalization spline. r12 established the
//      residency pin (~5.5 waves/CU regardless of grid/blockshape): the remaining stall
//      is not source-addressable; the only remaining lever is per-wave issue count.
__global__ __launch_bounds__(64) void nsf_main_v13(
    const float* __restrict__ x,
    const v8h* __restrict__ wsv,
    float* __restrict__ out, float* __restrict__ slots)
{
    __shared__ __align__(16) _Float16 smem[2 * SEGF16];   // 8448 B
    const int lane = threadIdx.x & 63;
    const int q = lane >> 4, l15 = lane & 15;
    _Float16* segA = &smem[0];
    _Float16* segB = &smem[SEGF16];
    const int pr = lane >> 1, pc = lane & 1;

    const float4* xv = (const float4*)x;
    float4* ov = (float4*)out;

    // prefetch registers (next pair's inputs)
    float4 ph_n = make_float4(0.f, 0.f, 0.f, 0.f);
    float uA0_n = 0.f, uA1_n = 0.f, uB0_n = 0.f, uB1_n = 0.f;
    float4 f0_n = ph_n, f1_n = ph_n, g0_n = ph_n, g1_n = ph_n;

    auto PREF = [&](int p) {
        const int R0 = p * 32;
        ph_n  = xv[(R0 + pr) * 4 + pc];
        uA0_n = x[(R0 + l15) * 16 + 8 + q];
        uA1_n = x[(R0 + l15) * 16 + 12 + q];
        uB0_n = x[(R0 + 16 + l15) * 16 + 8 + q];
        uB1_n = x[(R0 + 16 + l15) * 16 + 12 + q];
        if (lane < 16) {
            f0_n = xv[(R0 + lane) * 4 + 0];
            f1_n = xv[(R0 + lane) * 4 + 1];
            g0_n = xv[(R0 + 16 + lane) * 4 + 0];
            g1_n = xv[(R0 + 16 + lane) * 4 + 1];
        }
    };

    PREF(blockIdx.x);
    float ldacc = 0.0f;

    #pragma unroll 1
    for (int it = 0; it < ITERS; ++it) {
        // consume prefetched set (single waitcnt here), then immediately issue next prefetch
        const int pcur = it * NBLK + blockIdx.x;
        const int R0 = pcur * 32;                         // tile A: R0.., tile B: R0+16..
        const float4 phc = ph_n;
        const float uA0 = uA0_n, uA1 = uA1_n, uB0 = uB0_n, uB1 = uB1_n;
        const float4 f0 = f0_n, f1 = f1_n, g0 = g0_n, g1 = g1_n;
        if (it < ITERS - 1) PREF((it + 1) * NBLK + blockIdx.x);

        // passthrough of the 8 scale dims (coalesced float4)
        ov[(R0 + pr) * 4 + pc] = phc;

        // ---- phase 0: zd fragments for both tiles (k<8 real, k=8 -> 1.0 bias row) ----
        v8h aA, aB;
        #pragma unroll
        for (int j = 0; j < 8; ++j) { aA[j] = (_Float16)0.0f; aB[j] = (_Float16)0.0f; }
        if (lane < 16) {
            aA[0] = (_Float16)f0.x; aA[1] = (_Float16)f0.y; aA[2] = (_Float16)f0.z; aA[3] = (_Float16)f0.w;
            aA[4] = (_Float16)f1.x; aA[5] = (_Float16)f1.y; aA[6] = (_Float16)f1.z; aA[7] = (_Float16)f1.w;
            aB[0] = (_Float16)g0.x; aB[1] = (_Float16)g0.y; aB[2] = (_Float16)g0.z; aB[3] = (_Float16)g0.w;
            aB[4] = (_Float16)g1.x; aB[5] = (_Float16)g1.y; aB[6] = (_Float16)g1.z; aB[7] = (_Float16)g1.w;
        }
        if (q == 1) { aA[0] = (_Float16)1.0f; aB[0] = (_Float16)1.0f; }   // k=8: bias row

        // ---- phase 1: h1 = tanh(zd @ [w0;b0]) -> rows stride HS=84 ----
        #pragma unroll
        for (int t = 0; t < 4; ++t) {
            const v8h b = wsv[W0_OFF + t * 64 + lane];
            v4f cA = __builtin_amdgcn_mfma_f32_16x16x32_f16(b, aA, (v4f)(0.0f), 0, 0, 0);
            v4f cB = __builtin_amdgcn_mfma_f32_16x16x32_f16(b, aB, (v4f)(0.0f), 0, 0, 0);
            v4h pA, pB;
            #pragma unroll
            for (int rg = 0; rg < 4; ++rg) {
                pA[rg] = (_Float16)fast_tanh(cA[rg]);
                pB[rg] = (_Float16)fast_tanh(cB[rg]);
            }
            const int o = l15 * HS + t * 16 + q * 4;
            *(v4h*)&segA[o] = pA;
            *(v4h*)&segB[o] = pB;
        }

        // ---- phase 2: h2 = tanh(h1 @ [w1;b1]) (in-order DS: reads precede overwrites) ----
        v8h A0A, A1A, A0B, A1B;
        {
            const int o0 = l15 * HS + q * 8;
            const int o1 = l15 * HS + 32 + q * 8;
            const v4h a0l = *(const v4h*)&segA[o0], a0h = *(const v4h*)&segA[o0 + 4];
            const v4h a1l = *(const v4h*)&segA[o1], a1h = *(const v4h*)&segA[o1 + 4];
            const v4h b0l = *(const v4h*)&segB[o0], b0h = *(const v4h*)&segB[o0 + 4];
            const v4h b1l = *(const v4h*)&segB[o1], b1h = *(const v4h*)&segB[o1 + 4];
            #pragma unroll
            for (int j = 0; j < 4; ++j) {
                A0A[j] = a0l[j]; A0A[4 + j] = a0h[j];
                A1A[j] = a1l[j]; A1A[4 + j] = a1h[j];
                A0B[j] = b0l[j]; A0B[4 + j] = b0h[j];
                A1B[j] = b1l[j]; A1B[4 + j] = b1h[j];
            }
        }
        if (q == 2) { A1A[2] = (_Float16)1.0f; A1B[2] = (_Float16)1.0f; }   // k=50: bias row
        #pragma unroll
        for (int t = 0; t < 4; ++t) {
            const v8h bf0 = wsv[W1_OFF + t * 64 + lane];
            const v8h bf1 = wsv[W1_OFF + 256 + t * 64 + lane];
            v4f cA = __builtin_amdgcn_mfma_f32_16x16x32_f16(bf0, A0A, (v4f)(0.0f), 0, 0, 0);
            cA = __builtin_amdgcn_mfma_f32_16x16x32_f16(bf1, A1A, cA, 0, 0, 0);
            v4f cB = __builtin_amdgcn_mfma_f32_16x16x32_f16(bf0, A0B, (v4f)(0.0f), 0, 0, 0);
            cB = __builtin_amdgcn_mfma_f32_16x16x32_f16(bf1, A1B, cB, 0, 0, 0);
            v4h pA, pB;
            #pragma unroll
            for (int rg = 0; rg < 4; ++rg) {
                pA[rg] = (_Float16)fast_tanh(cA[rg]);
                pB[rg] = (_Float16)fast_tanh(cB[rg]);
            }
            const int o = l15 * HS + t * 16 + q * 4;
            *(v4h*)&segA[o] = pA;
            *(v4h*)&segB[o] = pB;
        }

        // ---- phase 3 h2-frags (reload, b64 pairs) ----
        {
            const int o0 = l15 * HS + q * 8;
            const int o1 = l15 * HS + 32 + q * 8;
            const v4h a0l = *(const v4h*)&segA[o0], a0h = *(const v4h*)&segA[o0 + 4];
            const v4h a1l = *(const v4h*)&segA[o1], a1h = *(const v4h*)&segA[o1 + 4];
            const v4h b0l = *(const v4h*)&segB[o0], b0h = *(const v4h*)&segB[o0 + 4];
            const v4h b1l = *(const v4h*)&segB[o1], b1h = *(const v4h*)&segB[o1 + 4];
            #pragma unroll
            for (int j = 0; j < 4; ++j) {
                A0A[j] = a0l[j]; A0A[4 + j] = a0h[j];
                A1A[j] = a1l[j]; A1A[4 + j] = a1h[j];
                A0B[j] = b0l[j]; A0B[4 + j] = b0h[j];
                A1B[j] = b1l[j]; A1B[4 + j] = b1h[j];
            }
        }
        if (q == 2) { A1A[2] = (_Float16)1.0f; A1B[2] = (_Float16)1.0f; }   // k=50: bias row

        // ---- phase 3 first half: dims 0-3 (t = 0..7) -> slots 0..3, stride SROW=132 ----
        #pragma unroll 2
        for (int t = 0; t < 8; ++t) {
            const v8h bf0 = wsv[WC_OFF + t * 64 + lane];
            const v8h bf1 = wsv[WC_OFF + 1024 + t * 64 + lane];
            v4f cA = __builtin_amdgcn_mfma_f32_16x16x32_f16(bf0, A0A, (v4f)(0.0f), 0, 0, 0);
            cA = __builtin_amdgcn_mfma_f32_16x16x32_f16(bf1, A1A, cA, 0, 0, 0);
            v4f cB = __builtin_amdgcn_mfma_f32_16x16x32_f16(bf0, A0B, (v4f)(0.0f), 0, 0, 0);
            cB = __builtin_amdgcn_mfma_f32_16x16x32_f16(bf1, A1B, cB, 0, 0, 0);
            v4h pA, pB;
            #pragma unroll
            for (int rg = 0; rg < 4; ++rg) { pA[rg] = (_Float16)cA[rg]; pB[rg] = (_Float16)cB[rg]; }
            const int o = l15 * SROW + t * 16 + q * 4;
            *(v4h*)&segA[o] = pA;
            *(v4h*)&segB[o] = pB;
        }

        // ---- epilogue tasks tt=0 (d = q): in-order DS reads precede second-half overwrites ----
        spline_task(segA, l15 * SROW + q * 32, uA0, R0 + l15, q, out, ldacc);
        spline_task(segB, l15 * SROW + q * 32, uB0, R0 + 16 + l15, q, out, ldacc);

        // ---- phase 3 second half: dims 4-7 (t = 8..15) -> SAME slots 0..3 (buffer reuse) ----
        #pragma unroll 2
        for (int t = 8; t < 16; ++t) {
            const v8h bf0 = wsv[WC_OFF + t * 64 + lane];
            const v8h bf1 = wsv[WC_OFF + 1024 + t * 64 + lane];
            v4f cA = __builtin_amdgcn_mfma_f32_16x16x32_f16(bf0, A0A, (v4f)(0.0f), 0, 0, 0);
            cA = __builtin_amdgcn_mfma_f32_16x16x32_f16(bf1, A1A, cA, 0, 0, 0);
            v4f cB = __builtin_amdgcn_mfma_f32_16x16x32_f16(bf0, A0B, (v4f)(0.0f), 0, 0, 0);
            cB = __builtin_amdgcn_mfma_f32_16x16x32_f16(bf1, A1B, cB, 0, 0, 0);
            v4h pA, pB;
            #pragma unroll
            for (int rg = 0; rg < 4; ++rg) { pA[rg] = (_Float16)cA[rg]; pB[rg] = (_Float16)cB[rg]; }
            const int o = l15 * SROW + (t - 8) * 16 + q * 4;
            *(v4h*)&segA[o] = pA;
            *(v4h*)&segB[o] = pB;
        }

        // ---- epilogue tasks tt=1 (d = q+4, same slots) ----
        spline_task(segA, l15 * SROW + q * 32, uA1, R0 + l15, q + 4, out, ldacc);
        spline_task(segB, l15 * SROW + q * 32, uB1, R0 + 16 + l15, q + 4, out, ldacc);
    }

    // ---- logdet: one wave shuffle-reduce + atomic per persistent wave ----
    #pragma unroll
    for (int off = 32; off > 0; off >>= 1) ldacc += __shfl_down(ldacc, off);
    if (lane == 0) atomicAdd(&slots[blockIdx.x & 63], ldacc);
}

// ---- finish: sum the 64 partial slots into the scalar logdet output ----
__global__ void nsf_finish(const float* __restrict__ slots, float* __restrict__ ldp) {
    float v = slots[threadIdx.x];
    #pragma unroll
    for (int off = 32; off > 0; off >>= 1) v += __shfl_down(v, off);
    if (threadIdx.x == 0) *ldp = v;
}

extern "C" void kernel_launch(void* const* d_in, const int* in_sizes, int n_in,
                              void* d_out, int out_size, void* d_ws, size_t ws_size,
                              hipStream_t stream) {
    const float* x  = (const float*)d_in[0];
    const float* w0 = (const float*)d_in[1];
    const float* b0 = (const float*)d_in[2];
    const float* w1 = (const float*)d_in[3];
    const float* b1 = (const float*)d_in[4];
    const float* ww = (const float*)d_in[5];
    const float* bw = (const float*)d_in[6];
    const float* wh = (const float*)d_in[7];
    const float* bh = (const float*)d_in[8];
    const float* wd = (const float*)d_in[9];
    const float* bd = (const float*)d_in[10];

    float* out = (float*)d_out;
    float* ldp = out + (size_t)NROWS * 16;   // scalar logdet sum slot
    v8h* wsv = (v8h*)d_ws;                   // 45 KB packed B-fragments (bias folded)
    float* wsf = (float*)d_ws;               // f32 view for slots
    float* slots = wsf + SLOTS_OFF;

    hipLaunchKernelGGL(nsf_prep, dim3((FRAG_TOTAL + 255) / 256), dim3(256), 0, stream,
                       w0, b0, w1, b1, ww, bw, wh, bh, wd, bd, wsv, wsf);
    hipLaunchKernelGGL(nsf_main_v13, dim3(NBLK), dim3(64), 0, stream,
                       x, wsv, out, slots);
    hipLaunchKernelGGL(nsf_finish, dim3(1), dim3(64), 0, stream, slots, ldp);
}